// Round 4
// baseline (51.331 us; speedup 1.0000x reference)
//
#include <hip/hip_runtime.h>

#define NB 64
#define NP 32768
#define NA 14
#define NC 10
#define NANCH (NB * NP)            // 2097152 anchors
#define TILE 256                   // anchors per block
#define MAIN_BLOCKS (NANCH / TILE) // 8192

// ws layout (doubles):
//   ws[0            .. MAIN_BLOCKS-1]   per-block loss partial
//   ws[MAIN_BLOCKS  .. 2*MAIN_BLOCKS-1] per-block pos-count partial
//   ws[ACC_MINE]  mined-negative loss sum (atomicAdd; zeroed by ssd_main)
//   ws[DONE_SLOT] ticket counter (u32 in low word; zeroed by ssd_main)
// Everything finish reads is written by main (or by finish itself) each
// launch -> no memset, safe under harness 0xAA poisoning.
#define ACC_MINE  (2 * MAIN_BLOCKS)
#define DONE_SLOT (2 * MAIN_BLOCKS + 1)

__global__ __launch_bounds__(256) void ssd_main(
    const float* __restrict__ p,
    const float* __restrict__ loc_t,
    const int* __restrict__ conf_t,
    double* __restrict__ ws)
{
    const int tid = threadIdx.x;
    if (blockIdx.x == 0 && tid == 0) {
        ws[ACC_MINE] = 0.0;
        *reinterpret_cast<unsigned long long*>(ws + DONE_SLOT) = 0ull;
    }

    // p-tile staged in LDS: 256 anchors x 14 floats = 14336 B
    __shared__ float sp[TILE * NA];

    const size_t abase = (size_t)blockIdx.x * TILE;   // first anchor of tile
    const size_t fbase = abase * NA;                  // float offset into p

    // ---- coalesced stage: 896 float4 chunks, lane-contiguous ----
    const float4* psrc = reinterpret_cast<const float4*>(p + fbase);
    float4* sdst = reinterpret_cast<float4*>(sp);
#pragma unroll
    for (int k = 0; k < 3; ++k)
        sdst[tid + k * 256] = psrc[tid + k * 256];
    if (tid < 128)
        sdst[768 + tid] = psrc[768 + tid];

    // ---- per-anchor direct loads (already lane-contiguous) ----
    float4 lt = reinterpret_cast<const float4*>(loc_t)[abase + tid];
    int t = conf_t[abase + tid];

    __syncthreads();

    // ---- read own anchor row from LDS (8B-aligned float2 reads) ----
    float x[14];
    const float2* row = reinterpret_cast<const float2*>(&sp[tid * NA]);
#pragma unroll
    for (int j = 0; j < 7; ++j) {
        float2 w = row[j];
        x[2 * j]     = w.x;
        x[2 * j + 1] = w.y;
    }

    // stable logsumexp over conf logits x[4..13]
    float m = x[4];
#pragma unroll
    for (int j = 5; j < 14; ++j) m = fmaxf(m, x[j]);
    float s = 0.f;
#pragma unroll
    for (int j = 4; j < 14; ++j) s += __expf(x[j] - m);
    float lse = m + __logf(s);

    // target logit via select chain (no runtime register indexing)
    float tgt = x[4];
#pragma unroll
    for (int j = 1; j < 10; ++j) tgt = (t == j) ? x[4 + j] : tgt;
    float ce = lse - tgt;

    float loss = 0.f;
    int cnt = 0;
    if (t > 0) {
        loss = ce;
        const float* ltf = reinterpret_cast<const float*>(&lt);
#pragma unroll
        for (int j = 0; j < 4; ++j) {
            float d  = x[j] - ltf[j];
            float ad = fabsf(d);
            loss += (ad < 1.f) ? (0.5f * d * d) : (ad - 0.5f);
        }
        cnt = 1;
    }

    // ---- wave64 reduce in double, cross-wave via LDS, 1 STORE per block ----
    double dl = (double)loss;
#pragma unroll
    for (int off = 32; off > 0; off >>= 1) {
        dl  += __shfl_down(dl, off, 64);
        cnt += __shfl_down(cnt, off, 64);
    }
    __shared__ double sL[4];
    __shared__ int    sC[4];
    int lane = tid & 63, wid = tid >> 6;
    if (lane == 0) { sL[wid] = dl; sC[wid] = cnt; }
    __syncthreads();
    if (tid == 0) {
        ws[blockIdx.x] = sL[0] + sL[1] + sL[2] + sL[3];
        ws[MAIN_BLOCKS + blockIdx.x] =
            (double)(sC[0] + sC[1] + sC[2] + sC[3]);
    }
}

// loss_c for anchor i of a row: ce if negative anchor, else 0.
__device__ __forceinline__ float neg_conf_loss(
    const float* __restrict__ prow, const int* __restrict__ crow, int i)
{
    int t = crow[i];
    if (t > 0) return 0.f;
    const float* v = prow + (size_t)i * NA + 4;
    float m = v[0];
#pragma unroll
    for (int j = 1; j < NC; ++j) m = fmaxf(m, v[j]);
    float s = 0.f;
#pragma unroll
    for (int j = 0; j < NC; ++j) s += __expf(v[j] - m);
    return (m + __logf(s)) - v[0];   // t == 0 -> target logit is v[0]
}

// Fused: num_pos reduce (redundant per block, bit-identical) + hard-negative
// mining (general path; early-skip when num_neg <= 0, as for bench inputs)
// + last-block final reduce & output write.
__global__ __launch_bounds__(256) void ssd_finish(
    const float* __restrict__ p,
    const int* __restrict__ conf_t,
    double* __restrict__ ws,
    float* __restrict__ out)
{
    const int tid = threadIdx.x;
    int lane = tid & 63, wid = tid >> 6;
    __shared__ double sR[4];
    __shared__ double s_np;

    // ---- 1. num_pos: every block reduces cnt partials identically ----
    double c = 0.0;
    for (int i = tid; i < MAIN_BLOCKS; i += 256)
        c += ws[MAIN_BLOCKS + i];
#pragma unroll
    for (int off = 32; off > 0; off >>= 1)
        c += __shfl_down(c, off, 64);
    if (lane == 0) sR[wid] = c;
    __syncthreads();
    if (tid == 0) s_np = sR[0] + sR[1] + sR[2] + sR[3];
    __syncthreads();
    const double np_d = s_np;

    // ---- 2. hard-negative mining (skipped when num_neg <= 0) ----
    long long np = (long long)np_d;
    long long nn = 3 * np;
    long long ub = (long long)NP - np;
    if (ub < nn) nn = ub;

    if (nn > 0) {
        const float* prow = p + (size_t)blockIdx.x * NP * NA;
        const int*   crow = conf_t + (size_t)blockIdx.x * NP;

        __shared__ unsigned int hist[256];
        __shared__ unsigned int s_prefix;
        __shared__ long long    s_want;

        unsigned int prefix = 0;
        long long want = nn;                  // 1-indexed rank (largest)

        // 8-bit MSB-first radix select on float bits (loss_c >= 0).
        for (int pass = 0; pass < 4; ++pass) {
            int shift = 24 - 8 * pass;
            hist[tid] = 0;
            __syncthreads();
            for (int i = tid; i < NP; i += 256) {
                unsigned int k = __float_as_uint(neg_conf_loss(prow, crow, i));
                bool match = (pass == 0) || ((k >> (shift + 8)) == prefix);
                if (match) atomicAdd(&hist[(k >> shift) & 255u], 1u);
            }
            __syncthreads();
            if (tid == 0) {
                unsigned long long cum = 0;
                int d = 255;
                for (; d > 0; --d) {          // falls through to d=0
                    unsigned long long h = hist[d];
                    if (cum + h >= (unsigned long long)want) break;
                    cum += h;
                }
                s_want   = want - (long long)cum;
                s_prefix = (prefix << 8) | (unsigned int)d;
            }
            __syncthreads();
            prefix = s_prefix;
            want   = s_want;
            __syncthreads();
        }

        float T = __uint_as_float(prefix);    // nn-th largest value
        double sgt = 0.0;
        long long cgt = 0;
        for (int i = tid; i < NP; i += 256) {
            float lc = neg_conf_loss(prow, crow, i);
            if (__float_as_uint(lc) > prefix) { sgt += (double)lc; ++cgt; }
        }
#pragma unroll
        for (int off = 32; off > 0; off >>= 1) {
            sgt += __shfl_down(sgt, off, 64);
            cgt += __shfl_down(cgt, off, 64);
        }
        __shared__ double    rL[4];
        __shared__ long long rC[4];
        if (lane == 0) { rL[wid] = sgt; rC[wid] = cgt; }
        __syncthreads();
        if (tid == 0) {
            double stot = rL[0] + rL[1] + rL[2] + rL[3];
            long long ctot = rC[0] + rC[1] + rC[2] + rC[3];
            double rowsum = stot + (double)(nn - ctot) * (double)T;
            atomicAdd(&ws[ACC_MINE], rowsum);   // device-scope, coherent
        }
    }

    // ---- 3. ticket: last block to finish produces the output ----
    __threadfence();
    __shared__ unsigned int s_ticket;
    if (tid == 0)
        s_ticket = atomicAdd(reinterpret_cast<unsigned int*>(ws + DONE_SLOT), 1u);
    __syncthreads();

    if (s_ticket == NB - 1) {
        double l = 0.0;
        for (int i = tid; i < MAIN_BLOCKS; i += 256)
            l += ws[i];
#pragma unroll
        for (int off = 32; off > 0; off >>= 1)
            l += __shfl_down(l, off, 64);
        __shared__ double fL[4];
        if (lane == 0) fL[wid] = l;
        __syncthreads();
        if (tid == 0) {
            double mined = __hip_atomic_load(&ws[ACC_MINE], __ATOMIC_RELAXED,
                                             __HIP_MEMORY_SCOPE_AGENT);
            double total = fL[0] + fL[1] + fL[2] + fL[3] + mined;
            out[0] = (float)(total / np_d);
        }
    }
}

extern "C" void kernel_launch(void* const* d_in, const int* in_sizes, int n_in,
                              void* d_out, int out_size, void* d_ws, size_t ws_size,
                              hipStream_t stream)
{
    const float* p      = (const float*)d_in[0];
    const float* loc_t  = (const float*)d_in[1];
    const int*   conf_t = (const int*)d_in[2];
    float*  out = (float*)d_out;
    double* ws  = (double*)d_ws;

    ssd_main<<<MAIN_BLOCKS, 256, 0, stream>>>(p, loc_t, conf_t, ws);
    ssd_finish<<<NB, 256, 0, stream>>>(p, conf_t, ws, out);
}

// Round 5
// 41.504 us; speedup vs baseline: 1.2368x; 1.2368x over previous
//
#include <hip/hip_runtime.h>

#define NB 64
#define NP 32768
#define NA 14
#define NC 10
#define NANCH (NB * NP)            // 2097152 anchors
#define TILE 256                   // anchors per block
#define MAIN_BLOCKS (NANCH / TILE) // 8192

// ws layout (doubles):
//   ws[0            .. MAIN_BLOCKS-1]   per-block loss partial
//   ws[MAIN_BLOCKS  .. 2*MAIN_BLOCKS-1] per-block pos-count partial
//   ws[ACC_LOSS]  total loss (reduce writes; mine atomicAdds on slow path)
//   ws[ACC_NPOS]  num_pos    (reduce writes)
//   ws[DONE_SLOT] ticket u64 (reduce zeroes; mine's slow path uses)
// Every location finish-path reads is written earlier in the same launch ->
// no memset, safe under harness 0xAA poisoning and graph replay.
#define ACC_LOSS  (2 * MAIN_BLOCKS)
#define ACC_NPOS  (2 * MAIN_BLOCKS + 1)
#define DONE_SLOT (2 * MAIN_BLOCKS + 2)

typedef const __attribute__((address_space(1))) void* gptr_t;
typedef __attribute__((address_space(3))) void* lptr_t;

__global__ __launch_bounds__(256) void ssd_main(
    const float* __restrict__ p,
    const float* __restrict__ loc_t,
    const int* __restrict__ conf_t,
    double* __restrict__ ws)
{
    // p-tile staged in LDS: 256 anchors x 14 floats = 14336 B = 896 x 16B
    __shared__ float sp[TILE * NA];

    const int tid  = threadIdx.x;
    const int lane = tid & 63, wid = tid >> 6;
    const size_t abase = (size_t)blockIdx.x * TILE;   // first anchor of tile
    const size_t fbase = abase * NA;                  // float offset into p

    // ---- async global->LDS staging: 16B/lane, wave-uniform LDS base ----
    // chunk c (16B) lives at LDS byte c*16; wave w, iter k covers chunks
    // [k*256 + w*64, +64). Global src is per-lane, LDS dest linear in lane.
    const char* gsrc  = reinterpret_cast<const char*>(p + fbase);
    char*       sbase = reinterpret_cast<char*>(sp);
#pragma unroll
    for (int k = 0; k < 3; ++k) {
        const int c0 = k * 256 + wid * 64;            // wave-uniform
        __builtin_amdgcn_global_load_lds(
            (gptr_t)(gsrc + (size_t)(c0 + lane) * 16),
            (lptr_t)(sbase + (size_t)c0 * 16), 16, 0, 0);
    }
    if (wid < 2) {                                    // tail 128 chunks
        const int c0 = 768 + wid * 64;                // wave-uniform
        __builtin_amdgcn_global_load_lds(
            (gptr_t)(gsrc + (size_t)(c0 + lane) * 16),
            (lptr_t)(sbase + (size_t)c0 * 16), 16, 0, 0);
    }

    // ---- per-anchor direct loads (lane-contiguous) ----
    float4 lt = reinterpret_cast<const float4*>(loc_t)[abase + tid];
    int t = conf_t[abase + tid];

    __syncthreads();   // drains vmcnt(0) -> LDS tile complete

    // ---- read own anchor row from LDS (8B-aligned float2 reads) ----
    float x[14];
    const float2* row = reinterpret_cast<const float2*>(&sp[tid * NA]);
#pragma unroll
    for (int j = 0; j < 7; ++j) {
        float2 w = row[j];
        x[2 * j]     = w.x;
        x[2 * j + 1] = w.y;
    }

    // stable logsumexp over conf logits x[4..13]
    float m = x[4];
#pragma unroll
    for (int j = 5; j < 14; ++j) m = fmaxf(m, x[j]);
    float s = 0.f;
#pragma unroll
    for (int j = 4; j < 14; ++j) s += __expf(x[j] - m);
    float lse = m + __logf(s);

    // target logit via select chain (no runtime register indexing)
    float tgt = x[4];
#pragma unroll
    for (int j = 1; j < 10; ++j) tgt = (t == j) ? x[4 + j] : tgt;
    float ce = lse - tgt;

    float loss = 0.f;
    int cnt = 0;
    if (t > 0) {
        loss = ce;
        const float* ltf = reinterpret_cast<const float*>(&lt);
#pragma unroll
        for (int j = 0; j < 4; ++j) {
            float d  = x[j] - ltf[j];
            float ad = fabsf(d);
            loss += (ad < 1.f) ? (0.5f * d * d) : (ad - 0.5f);
        }
        cnt = 1;
    }

    // ---- wave64 reduce in double, cross-wave via LDS, 1 STORE per block ----
    double dl = (double)loss;
#pragma unroll
    for (int off = 32; off > 0; off >>= 1) {
        dl  += __shfl_down(dl, off, 64);
        cnt += __shfl_down(cnt, off, 64);
    }
    __shared__ double sL[4];
    __shared__ int    sC[4];
    if (lane == 0) { sL[wid] = dl; sC[wid] = cnt; }
    __syncthreads();
    if (tid == 0) {
        ws[blockIdx.x] = sL[0] + sL[1] + sL[2] + sL[3];
        ws[MAIN_BLOCKS + blockIdx.x] =
            (double)(sC[0] + sC[1] + sC[2] + sC[3]);
    }
}

// 1 block: sum partials; on the fast path (num_neg<=0) also writes out.
__global__ __launch_bounds__(256) void ssd_reduce(double* __restrict__ ws,
                                                  float* __restrict__ out)
{
    const int tid = threadIdx.x;
    double l = 0.0, c = 0.0;
    for (int i = tid; i < MAIN_BLOCKS; i += 256) {
        l += ws[i];
        c += ws[MAIN_BLOCKS + i];
    }
#pragma unroll
    for (int off = 32; off > 0; off >>= 1) {
        l += __shfl_down(l, off, 64);
        c += __shfl_down(c, off, 64);
    }
    __shared__ double sL[4], sC[4];
    int lane = tid & 63, wid = tid >> 6;
    if (lane == 0) { sL[wid] = l; sC[wid] = c; }
    __syncthreads();
    if (tid == 0) {
        double L  = sL[0] + sL[1] + sL[2] + sL[3];
        double np = sC[0] + sC[1] + sC[2] + sC[3];
        ws[ACC_LOSS] = L;
        ws[ACC_NPOS] = np;
        *reinterpret_cast<unsigned long long*>(ws + DONE_SLOT) = 0ull;
        long long npi = (long long)np;
        long long nn = 3 * npi;
        long long ub = (long long)NP - npi;
        if (ub < nn) nn = ub;
        if (nn <= 0) out[0] = (float)(L / np);   // fast path: done here
    }
}

// loss_c for anchor i of a row: ce if negative anchor, else 0.
__device__ __forceinline__ float neg_conf_loss(
    const float* __restrict__ prow, const int* __restrict__ crow, int i)
{
    int t = crow[i];
    if (t > 0) return 0.f;
    const float* v = prow + (size_t)i * NA + 4;
    float m = v[0];
#pragma unroll
    for (int j = 1; j < NC; ++j) m = fmaxf(m, v[j]);
    float s = 0.f;
#pragma unroll
    for (int j = 0; j < NC; ++j) s += __expf(v[j] - m);
    return (m + __logf(s)) - v[0];   // t == 0 -> target logit is v[0]
}

// General hard-negative mining; early-exits (bench path) when num_neg<=0.
// Slow path: radix-select top-nn per row, atomicAdd into ACC_LOSS, ticketed
// last block divides and writes out.
__global__ __launch_bounds__(256) void ssd_mine(
    const float* __restrict__ p,
    const int* __restrict__ conf_t,
    double* __restrict__ ws,
    float* __restrict__ out)
{
    const double np_d = ws[ACC_NPOS];
    long long np = (long long)np_d;
    long long nn = 3 * np;
    long long ub = (long long)NP - np;
    if (ub < nn) nn = ub;
    if (nn <= 0) return;                      // <- taken for bench inputs

    const int tid = threadIdx.x;
    int lane = tid & 63, wid = tid >> 6;
    const float* prow = p + (size_t)blockIdx.x * NP * NA;
    const int*   crow = conf_t + (size_t)blockIdx.x * NP;

    __shared__ unsigned int hist[256];
    __shared__ unsigned int s_prefix;
    __shared__ long long    s_want;

    unsigned int prefix = 0;
    long long want = nn;                      // 1-indexed rank (largest)

    // 8-bit MSB-first radix select on float bits (loss_c >= 0 -> monotone).
    for (int pass = 0; pass < 4; ++pass) {
        int shift = 24 - 8 * pass;
        hist[tid] = 0;
        __syncthreads();
        for (int i = tid; i < NP; i += 256) {
            unsigned int k = __float_as_uint(neg_conf_loss(prow, crow, i));
            bool match = (pass == 0) || ((k >> (shift + 8)) == prefix);
            if (match) atomicAdd(&hist[(k >> shift) & 255u], 1u);
        }
        __syncthreads();
        if (tid == 0) {
            unsigned long long cum = 0;
            int d = 255;
            for (; d > 0; --d) {              // falls through to d=0
                unsigned long long h = hist[d];
                if (cum + h >= (unsigned long long)want) break;
                cum += h;
            }
            s_want   = want - (long long)cum;
            s_prefix = (prefix << 8) | (unsigned int)d;
        }
        __syncthreads();
        prefix = s_prefix;
        want   = s_want;
        __syncthreads();
    }

    float T = __uint_as_float(prefix);        // nn-th largest value
    double sgt = 0.0;
    long long cgt = 0;
    for (int i = tid; i < NP; i += 256) {
        float lc = neg_conf_loss(prow, crow, i);
        if (__float_as_uint(lc) > prefix) { sgt += (double)lc; ++cgt; }
    }
#pragma unroll
    for (int off = 32; off > 0; off >>= 1) {
        sgt += __shfl_down(sgt, off, 64);
        cgt += __shfl_down(cgt, off, 64);
    }
    __shared__ double    rL[4];
    __shared__ long long rC[4];
    if (lane == 0) { rL[wid] = sgt; rC[wid] = cgt; }
    __syncthreads();
    if (tid == 0) {
        double stot = rL[0] + rL[1] + rL[2] + rL[3];
        long long ctot = rC[0] + rC[1] + rC[2] + rC[3];
        double rowsum = stot + (double)(nn - ctot) * (double)T;
        atomicAdd(&ws[ACC_LOSS], rowsum);     // device-scope
    }

    // ticket: last row-block computes the final output
    __threadfence();
    __shared__ unsigned int s_ticket;
    if (tid == 0)
        s_ticket = atomicAdd(reinterpret_cast<unsigned int*>(ws + DONE_SLOT), 1u);
    __syncthreads();
    if (s_ticket == NB - 1 && tid == 0) {
        double total = __hip_atomic_load(&ws[ACC_LOSS], __ATOMIC_RELAXED,
                                         __HIP_MEMORY_SCOPE_AGENT);
        out[0] = (float)(total / np_d);
    }
}

extern "C" void kernel_launch(void* const* d_in, const int* in_sizes, int n_in,
                              void* d_out, int out_size, void* d_ws, size_t ws_size,
                              hipStream_t stream)
{
    const float* p      = (const float*)d_in[0];
    const float* loc_t  = (const float*)d_in[1];
    const int*   conf_t = (const int*)d_in[2];
    float*  out = (float*)d_out;
    double* ws  = (double*)d_ws;

    ssd_main<<<MAIN_BLOCKS, 256, 0, stream>>>(p, loc_t, conf_t, ws);
    ssd_reduce<<<1, 256, 0, stream>>>(ws, out);
    ssd_mine<<<NB, 256, 0, stream>>>(p, conf_t, ws, out);
}

// Round 6
// 34.651 us; speedup vs baseline: 1.4814x; 1.1978x over previous
//
#include <hip/hip_runtime.h>

#define NB 64
#define NP 32768
#define NA 14
#define NC 10
#define NANCH (NB * NP)            // 2097152 anchors
#define TILE 256                   // anchors per LDS tile
#define TPB 4                      // tiles per block
#define MAIN_BLOCKS (NANCH / (TILE * TPB)) // 2048

// ws layout (doubles):
//   ws[0            .. MAIN_BLOCKS-1]   per-block loss partial
//   ws[MAIN_BLOCKS  .. 2*MAIN_BLOCKS-1] per-block pos-count partial
//   ws[ACC_LOSS]  total loss (reduce writes; mine atomicAdds on slow path)
//   ws[ACC_NPOS]  num_pos    (reduce writes)
//   ws[DONE_SLOT] ticket u64 (reduce zeroes; mine's slow path uses)
// Every location read on any path is written earlier in the same launch ->
// no memset, safe under harness 0xAA poisoning and graph replay.
#define ACC_LOSS  (2 * MAIN_BLOCKS)
#define ACC_NPOS  (2 * MAIN_BLOCKS + 1)
#define DONE_SLOT (2 * MAIN_BLOCKS + 2)

typedef const __attribute__((address_space(1))) void* gptr_t;
typedef __attribute__((address_space(3))) void* lptr_t;

__global__ __launch_bounds__(256) void ssd_main(
    const float* __restrict__ p,
    const float* __restrict__ loc_t,
    const int* __restrict__ conf_t,
    double* __restrict__ ws)
{
    // double-buffered p tiles: 2 x 256 anchors x 14 floats = 28672 B
    __shared__ float sp[2][TILE * NA];

    const int tid  = threadIdx.x;
    const int lane = tid & 63, wid = tid >> 6;
    const size_t tile0 = (size_t)blockIdx.x * TPB;

    // async global->LDS stage of one 14336B tile (896 x 16B chunks):
    // chunk c -> LDS byte c*16; wave-uniform LDS base, per-lane global src.
    auto stage = [&](int b, size_t tidx) {
        const char* gsrc  = reinterpret_cast<const char*>(p + tidx * (TILE * NA));
        char*       sbase = reinterpret_cast<char*>(sp[b]);
#pragma unroll
        for (int k = 0; k < 3; ++k) {
            const int c0 = k * 256 + wid * 64;        // wave-uniform
            __builtin_amdgcn_global_load_lds(
                (gptr_t)(gsrc + (size_t)(c0 + lane) * 16),
                (lptr_t)(sbase + (size_t)c0 * 16), 16, 0, 0);
        }
        if (wid < 2) {                                // tail 128 chunks
            const int c0 = 768 + wid * 64;
            __builtin_amdgcn_global_load_lds(
                (gptr_t)(gsrc + (size_t)(c0 + lane) * 16),
                (lptr_t)(sbase + (size_t)c0 * 16), 16, 0, 0);
        }
    };

    stage(0, tile0);                                  // prologue

    float lossAcc = 0.f;
    int   cntAcc  = 0;

#pragma unroll
    for (int it = 0; it < TPB; ++it) {
        const size_t abase = (tile0 + it) * TILE;
        // this tile's per-anchor direct loads (lane-contiguous), issued
        // before the barrier so they're in flight alongside the stage.
        float4 lt = reinterpret_cast<const float4*>(loc_t)[abase + tid];
        int t = conf_t[abase + tid];

        __syncthreads();   // drains vmcnt -> sp[it&1] complete; also
                           // guarantees prior compute finished reading
                           // the buffer the next prefetch will overwrite.

        if (it + 1 < TPB) stage((it + 1) & 1, tile0 + it + 1);  // prefetch

        // ---- read own anchor row from LDS (8B-aligned float2 reads) ----
        const float2* row =
            reinterpret_cast<const float2*>(&sp[it & 1][tid * NA]);
        float x[14];
#pragma unroll
        for (int j = 0; j < 7; ++j) {
            float2 w = row[j];
            x[2 * j]     = w.x;
            x[2 * j + 1] = w.y;
        }

        // stable logsumexp over conf logits x[4..13]
        float m = x[4];
#pragma unroll
        for (int j = 5; j < 14; ++j) m = fmaxf(m, x[j]);
        float s = 0.f;
#pragma unroll
        for (int j = 4; j < 14; ++j) s += __expf(x[j] - m);
        float lse = m + __logf(s);

        // target logit via select chain (no runtime register indexing)
        float tgt = x[4];
#pragma unroll
        for (int j = 1; j < 10; ++j) tgt = (t == j) ? x[4 + j] : tgt;
        float ce = lse - tgt;

        if (t > 0) {
            float l = ce;
            const float* ltf = reinterpret_cast<const float*>(&lt);
#pragma unroll
            for (int j = 0; j < 4; ++j) {
                float d  = x[j] - ltf[j];
                float ad = fabsf(d);
                l += (ad < 1.f) ? (0.5f * d * d) : (ad - 0.5f);
            }
            lossAcc += l;
            ++cntAcc;
        }
    }

    // ---- wave64 reduce in double, cross-wave via LDS, 1 STORE per block ----
    double dl = (double)lossAcc;
    int cnt = cntAcc;
#pragma unroll
    for (int off = 32; off > 0; off >>= 1) {
        dl  += __shfl_down(dl, off, 64);
        cnt += __shfl_down(cnt, off, 64);
    }
    __shared__ double sL[4];
    __shared__ int    sC[4];
    if (lane == 0) { sL[wid] = dl; sC[wid] = cnt; }
    __syncthreads();
    if (tid == 0) {
        ws[blockIdx.x] = sL[0] + sL[1] + sL[2] + sL[3];
        ws[MAIN_BLOCKS + blockIdx.x] =
            (double)(sC[0] + sC[1] + sC[2] + sC[3]);
    }
}

// 1 block: sum partials; on the fast path (num_neg<=0) also writes out.
__global__ __launch_bounds__(256) void ssd_reduce(double* __restrict__ ws,
                                                  float* __restrict__ out)
{
    const int tid = threadIdx.x;
    double l = 0.0, c = 0.0;
    for (int i = tid; i < MAIN_BLOCKS; i += 256) {
        l += ws[i];
        c += ws[MAIN_BLOCKS + i];
    }
#pragma unroll
    for (int off = 32; off > 0; off >>= 1) {
        l += __shfl_down(l, off, 64);
        c += __shfl_down(c, off, 64);
    }
    __shared__ double sL[4], sC[4];
    int lane = tid & 63, wid = tid >> 6;
    if (lane == 0) { sL[wid] = l; sC[wid] = c; }
    __syncthreads();
    if (tid == 0) {
        double L  = sL[0] + sL[1] + sL[2] + sL[3];
        double np = sC[0] + sC[1] + sC[2] + sC[3];
        ws[ACC_LOSS] = L;
        ws[ACC_NPOS] = np;
        *reinterpret_cast<unsigned long long*>(ws + DONE_SLOT) = 0ull;
        long long npi = (long long)np;
        long long nn = 3 * npi;
        long long ub = (long long)NP - npi;
        if (ub < nn) nn = ub;
        if (nn <= 0) out[0] = (float)(L / np);   // fast path: done here
    }
}

// loss_c for anchor i of a row: ce if negative anchor, else 0.
__device__ __forceinline__ float neg_conf_loss(
    const float* __restrict__ prow, const int* __restrict__ crow, int i)
{
    int t = crow[i];
    if (t > 0) return 0.f;
    const float* v = prow + (size_t)i * NA + 4;
    float m = v[0];
#pragma unroll
    for (int j = 1; j < NC; ++j) m = fmaxf(m, v[j]);
    float s = 0.f;
#pragma unroll
    for (int j = 0; j < NC; ++j) s += __expf(v[j] - m);
    return (m + __logf(s)) - v[0];   // t == 0 -> target logit is v[0]
}

// General hard-negative mining; early-exits (bench path) when num_neg<=0.
// Slow path: radix-select top-nn per row, atomicAdd into ACC_LOSS, ticketed
// last block divides and writes out.
__global__ __launch_bounds__(256) void ssd_mine(
    const float* __restrict__ p,
    const int* __restrict__ conf_t,
    double* __restrict__ ws,
    float* __restrict__ out)
{
    const double np_d = ws[ACC_NPOS];
    long long np = (long long)np_d;
    long long nn = 3 * np;
    long long ub = (long long)NP - np;
    if (ub < nn) nn = ub;
    if (nn <= 0) return;                      // <- taken for bench inputs

    const int tid = threadIdx.x;
    int lane = tid & 63, wid = tid >> 6;
    const float* prow = p + (size_t)blockIdx.x * NP * NA;
    const int*   crow = conf_t + (size_t)blockIdx.x * NP;

    __shared__ unsigned int hist[256];
    __shared__ unsigned int s_prefix;
    __shared__ long long    s_want;

    unsigned int prefix = 0;
    long long want = nn;                      // 1-indexed rank (largest)

    // 8-bit MSB-first radix select on float bits (loss_c >= 0 -> monotone).
    for (int pass = 0; pass < 4; ++pass) {
        int shift = 24 - 8 * pass;
        hist[tid] = 0;
        __syncthreads();
        for (int i = tid; i < NP; i += 256) {
            unsigned int k = __float_as_uint(neg_conf_loss(prow, crow, i));
            bool match = (pass == 0) || ((k >> (shift + 8)) == prefix);
            if (match) atomicAdd(&hist[(k >> shift) & 255u], 1u);
        }
        __syncthreads();
        if (tid == 0) {
            unsigned long long cum = 0;
            int d = 255;
            for (; d > 0; --d) {              // falls through to d=0
                unsigned long long h = hist[d];
                if (cum + h >= (unsigned long long)want) break;
                cum += h;
            }
            s_want   = want - (long long)cum;
            s_prefix = (prefix << 8) | (unsigned int)d;
        }
        __syncthreads();
        prefix = s_prefix;
        want   = s_want;
        __syncthreads();
    }

    float T = __uint_as_float(prefix);        // nn-th largest value
    double sgt = 0.0;
    long long cgt = 0;
    for (int i = tid; i < NP; i += 256) {
        float lc = neg_conf_loss(prow, crow, i);
        if (__float_as_uint(lc) > prefix) { sgt += (double)lc; ++cgt; }
    }
#pragma unroll
    for (int off = 32; off > 0; off >>= 1) {
        sgt += __shfl_down(sgt, off, 64);
        cgt += __shfl_down(cgt, off, 64);
    }
    __shared__ double    rL[4];
    __shared__ long long rC[4];
    if (lane == 0) { rL[wid] = sgt; rC[wid] = cgt; }
    __syncthreads();
    if (tid == 0) {
        double stot = rL[0] + rL[1] + rL[2] + rL[3];
        long long ctot = rC[0] + rC[1] + rC[2] + rC[3];
        double rowsum = stot + (double)(nn - ctot) * (double)T;
        atomicAdd(&ws[ACC_LOSS], rowsum);     // device-scope
    }

    // ticket: last row-block computes the final output
    __threadfence();
    __shared__ unsigned int s_ticket;
    if (tid == 0)
        s_ticket = atomicAdd(reinterpret_cast<unsigned int*>(ws + DONE_SLOT), 1u);
    __syncthreads();
    if (s_ticket == NB - 1 && tid == 0) {
        double total = __hip_atomic_load(&ws[ACC_LOSS], __ATOMIC_RELAXED,
                                         __HIP_MEMORY_SCOPE_AGENT);
        out[0] = (float)(total / np_d);
    }
}

extern "C" void kernel_launch(void* const* d_in, const int* in_sizes, int n_in,
                              void* d_out, int out_size, void* d_ws, size_t ws_size,
                              hipStream_t stream)
{
    const float* p      = (const float*)d_in[0];
    const float* loc_t  = (const float*)d_in[1];
    const int*   conf_t = (const int*)d_in[2];
    float*  out = (float*)d_out;
    double* ws  = (double*)d_ws;

    ssd_main<<<MAIN_BLOCKS, 256, 0, stream>>>(p, loc_t, conf_t, ws);
    ssd_reduce<<<1, 256, 0, stream>>>(ws, out);
    ssd_mine<<<NB, 256, 0, stream>>>(p, conf_t, ws, out);
}

// Round 7
// 33.565 us; speedup vs baseline: 1.5293x; 1.0323x over previous
//
#include <hip/hip_runtime.h>

#define NB 64
#define NP 32768
#define NA 14
#define NC 10
#define NANCH (NB * NP)            // 2097152 anchors
#define TILE 256                   // anchors per LDS tile
#define TPB 8                      // tiles per block
#define MAIN_BLOCKS (NANCH / (TILE * TPB)) // 1024

// ws layout (doubles):
//   ws[0            .. MAIN_BLOCKS-1]   per-block loss partial
//   ws[MAIN_BLOCKS  .. 2*MAIN_BLOCKS-1] per-block pos-count partial
//   ws[ACC_LOSS]  base loss total   (finish block 0 writes on slow path)
//   ws[ACC_MINE]  mined-neg sum     (zeroed by main; slow-path atomicAdd)
//   ws[DONE_SLOT] ticket u64        (zeroed by main; slow path only)
// Every location read on any path is written earlier in the same launch ->
// no memset, safe under harness 0xAA poisoning and graph replay.
#define ACC_LOSS  (2 * MAIN_BLOCKS)
#define ACC_MINE  (2 * MAIN_BLOCKS + 1)
#define DONE_SLOT (2 * MAIN_BLOCKS + 2)

typedef const __attribute__((address_space(1))) void* gptr_t;
typedef __attribute__((address_space(3))) void* lptr_t;

__global__ __launch_bounds__(256) void ssd_main(
    const float* __restrict__ p,
    const float* __restrict__ loc_t,
    const int* __restrict__ conf_t,
    double* __restrict__ ws)
{
    // double-buffered p tiles: 2 x 256 anchors x 14 floats = 28672 B
    __shared__ float sp[2][TILE * NA];

    const int tid  = threadIdx.x;
    const int lane = tid & 63, wid = tid >> 6;
    const size_t tile0 = (size_t)blockIdx.x * TPB;

    if (blockIdx.x == 0 && tid == 0) {
        ws[ACC_MINE] = 0.0;
        *reinterpret_cast<unsigned long long*>(ws + DONE_SLOT) = 0ull;
    }

    // async global->LDS stage of one 14336B tile (896 x 16B chunks):
    // chunk c -> LDS byte c*16; wave-uniform LDS base, per-lane global src.
    auto stage = [&](int b, size_t tidx) {
        const char* gsrc  = reinterpret_cast<const char*>(p + tidx * (TILE * NA));
        char*       sbase = reinterpret_cast<char*>(sp[b]);
#pragma unroll
        for (int k = 0; k < 3; ++k) {
            const int c0 = k * 256 + wid * 64;        // wave-uniform
            __builtin_amdgcn_global_load_lds(
                (gptr_t)(gsrc + (size_t)(c0 + lane) * 16),
                (lptr_t)(sbase + (size_t)c0 * 16), 16, 0, 0);
        }
        if (wid < 2) {                                // tail 128 chunks
            const int c0 = 768 + wid * 64;
            __builtin_amdgcn_global_load_lds(
                (gptr_t)(gsrc + (size_t)(c0 + lane) * 16),
                (lptr_t)(sbase + (size_t)c0 * 16), 16, 0, 0);
        }
    };

    // prologue: tile 0's stage + per-anchor loads all in flight together
    stage(0, tile0);
    float4 ltc = reinterpret_cast<const float4*>(loc_t)[tile0 * TILE + tid];
    int    tc  = conf_t[tile0 * TILE + tid];

    float lossAcc = 0.f;
    int   cntAcc  = 0;

#pragma unroll
    for (int it = 0; it < TPB; ++it) {
        __syncthreads();   // drains stage(it) + ltc/tc (issued a full
                           // compute phase ago, except tile 0) and protects
                           // the buffer the next prefetch overwrites.

        // issue next tile's stage + per-anchor loads NOW, so the next
        // barrier never waits on a fresh load (async-STAGE split).
        float4 ltn = ltc; int tn = tc;
        if (it + 1 < TPB) {
            stage((it + 1) & 1, tile0 + it + 1);
            const size_t nb = (tile0 + it + 1) * TILE;
            ltn = reinterpret_cast<const float4*>(loc_t)[nb + tid];
            tn  = conf_t[nb + tid];
        }

        // ---- read own anchor row from LDS (8B-aligned float2 reads) ----
        const float2* row =
            reinterpret_cast<const float2*>(&sp[it & 1][tid * NA]);
        float x[14];
#pragma unroll
        for (int j = 0; j < 7; ++j) {
            float2 w = row[j];
            x[2 * j]     = w.x;
            x[2 * j + 1] = w.y;
        }

        // stable logsumexp over conf logits x[4..13]
        float m = x[4];
#pragma unroll
        for (int j = 5; j < 14; ++j) m = fmaxf(m, x[j]);
        float s = 0.f;
#pragma unroll
        for (int j = 4; j < 14; ++j) s += __expf(x[j] - m);
        float lse = m + __logf(s);

        // target logit via select chain (no runtime register indexing)
        float tgt = x[4];
#pragma unroll
        for (int j = 1; j < 10; ++j) tgt = (tc == j) ? x[4 + j] : tgt;
        float ce = lse - tgt;

        if (tc > 0) {
            float l = ce;
            const float* ltf = reinterpret_cast<const float*>(&ltc);
#pragma unroll
            for (int j = 0; j < 4; ++j) {
                float d  = x[j] - ltf[j];
                float ad = fabsf(d);
                l += (ad < 1.f) ? (0.5f * d * d) : (ad - 0.5f);
            }
            lossAcc += l;
            ++cntAcc;
        }
        ltc = ltn; tc = tn;
    }

    // ---- wave64 reduce in double, cross-wave via LDS, 1 STORE per block ----
    double dl = (double)lossAcc;
    int cnt = cntAcc;
#pragma unroll
    for (int off = 32; off > 0; off >>= 1) {
        dl  += __shfl_down(dl, off, 64);
        cnt += __shfl_down(cnt, off, 64);
    }
    __shared__ double sL[4];
    __shared__ int    sC[4];
    if (lane == 0) { sL[wid] = dl; sC[wid] = cnt; }
    __syncthreads();
    if (tid == 0) {
        ws[blockIdx.x] = sL[0] + sL[1] + sL[2] + sL[3];
        ws[MAIN_BLOCKS + blockIdx.x] =
            (double)(sC[0] + sC[1] + sC[2] + sC[3]);
    }
}

// loss_c for anchor i of a row: ce if negative anchor, else 0.
__device__ __forceinline__ float neg_conf_loss(
    const float* __restrict__ prow, const int* __restrict__ crow, int i)
{
    int t = crow[i];
    if (t > 0) return 0.f;
    const float* v = prow + (size_t)i * NA + 4;
    float m = v[0];
#pragma unroll
    for (int j = 1; j < NC; ++j) m = fmaxf(m, v[j]);
    float s = 0.f;
#pragma unroll
    for (int j = 0; j < NC; ++j) s += __expf(v[j] - m);
    return (m + __logf(s)) - v[0];   // t == 0 -> target logit is v[0]
}

// Fused tail (64 blocks): every block reduces the count partials (16 KB,
// deterministic). Fast path (num_neg<=0, bench inputs): block 0 reduces the
// loss partials and writes out; no fences, tickets, or atomics. Slow path:
// per-row radix-select mining + ticketed combine.
__global__ __launch_bounds__(256) void ssd_finish(
    const float* __restrict__ p,
    const int* __restrict__ conf_t,
    double* __restrict__ ws,
    float* __restrict__ out)
{
    const int tid = threadIdx.x;
    const int lane = tid & 63, wid = tid >> 6;
    __shared__ double sR[4];
    __shared__ double s_np;

    // ---- 1. num_pos (identical in every block) ----
    double c = 0.0;
    for (int i = tid; i < MAIN_BLOCKS; i += 256)
        c += ws[MAIN_BLOCKS + i];
#pragma unroll
    for (int off = 32; off > 0; off >>= 1)
        c += __shfl_down(c, off, 64);
    if (lane == 0) sR[wid] = c;
    __syncthreads();
    if (tid == 0) s_np = sR[0] + sR[1] + sR[2] + sR[3];
    __syncthreads();
    const double np_d = s_np;

    long long np = (long long)np_d;
    long long nn = 3 * np;
    long long ub = (long long)NP - np;
    if (ub < nn) nn = ub;

    auto base_loss = [&]() -> double {          // reduce loss partials
        double l = 0.0;
        for (int i = tid; i < MAIN_BLOCKS; i += 256)
            l += ws[i];
#pragma unroll
        for (int off = 32; off > 0; off >>= 1)
            l += __shfl_down(l, off, 64);
        __shared__ double fL[4];
        if (lane == 0) fL[wid] = l;
        __syncthreads();
        return fL[0] + fL[1] + fL[2] + fL[3];   // valid in tid 0
    };

    if (nn <= 0) {                              // <- bench path
        if (blockIdx.x == 0) {
            double L = base_loss();
            if (tid == 0) out[0] = (float)(L / np_d);
        }
        return;
    }

    // ---- 2. slow path: mine this block's row ----
    const float* prow = p + (size_t)blockIdx.x * NP * NA;
    const int*   crow = conf_t + (size_t)blockIdx.x * NP;

    __shared__ unsigned int hist[256];
    __shared__ unsigned int s_prefix;
    __shared__ long long    s_want;

    unsigned int prefix = 0;
    long long want = nn;                        // 1-indexed rank (largest)

    // 8-bit MSB-first radix select on float bits (loss_c >= 0 -> monotone).
    for (int pass = 0; pass < 4; ++pass) {
        int shift = 24 - 8 * pass;
        hist[tid] = 0;
        __syncthreads();
        for (int i = tid; i < NP; i += 256) {
            unsigned int k = __float_as_uint(neg_conf_loss(prow, crow, i));
            bool match = (pass == 0) || ((k >> (shift + 8)) == prefix);
            if (match) atomicAdd(&hist[(k >> shift) & 255u], 1u);
        }
        __syncthreads();
        if (tid == 0) {
            unsigned long long cum = 0;
            int d = 255;
            for (; d > 0; --d) {                // falls through to d=0
                unsigned long long h = hist[d];
                if (cum + h >= (unsigned long long)want) break;
                cum += h;
            }
            s_want   = want - (long long)cum;
            s_prefix = (prefix << 8) | (unsigned int)d;
        }
        __syncthreads();
        prefix = s_prefix;
        want   = s_want;
        __syncthreads();
    }

    float T = __uint_as_float(prefix);          // nn-th largest value
    double sgt = 0.0;
    long long cgt = 0;
    for (int i = tid; i < NP; i += 256) {
        float lc = neg_conf_loss(prow, crow, i);
        if (__float_as_uint(lc) > prefix) { sgt += (double)lc; ++cgt; }
    }
#pragma unroll
    for (int off = 32; off > 0; off >>= 1) {
        sgt += __shfl_down(sgt, off, 64);
        cgt += __shfl_down(cgt, off, 64);
    }
    __shared__ double    rL[4];
    __shared__ long long rC[4];
    if (lane == 0) { rL[wid] = sgt; rC[wid] = cgt; }
    __syncthreads();
    if (tid == 0) {
        double stot = rL[0] + rL[1] + rL[2] + rL[3];
        long long ctot = rC[0] + rC[1] + rC[2] + rC[3];
        double rowsum = stot + (double)(nn - ctot) * (double)T;
        atomicAdd(&ws[ACC_MINE], rowsum);       // device-scope
    }

    if (blockIdx.x == 0) {                      // base loss alongside mining
        double L = base_loss();
        if (tid == 0) ws[ACC_LOSS] = L;
    }

    // ticket: last block combines and writes out
    __threadfence();
    __shared__ unsigned int s_ticket;
    if (tid == 0)
        s_ticket = atomicAdd(reinterpret_cast<unsigned int*>(ws + DONE_SLOT), 1u);
    __syncthreads();
    if (s_ticket == NB - 1 && tid == 0) {
        double base  = __hip_atomic_load(&ws[ACC_LOSS], __ATOMIC_RELAXED,
                                         __HIP_MEMORY_SCOPE_AGENT);
        double mined = __hip_atomic_load(&ws[ACC_MINE], __ATOMIC_RELAXED,
                                         __HIP_MEMORY_SCOPE_AGENT);
        out[0] = (float)((base + mined) / np_d);
    }
}

extern "C" void kernel_launch(void* const* d_in, const int* in_sizes, int n_in,
                              void* d_out, int out_size, void* d_ws, size_t ws_size,
                              hipStream_t stream)
{
    const float* p      = (const float*)d_in[0];
    const float* loc_t  = (const float*)d_in[1];
    const int*   conf_t = (const int*)d_in[2];
    float*  out = (float*)d_out;
    double* ws  = (double*)d_ws;

    ssd_main<<<MAIN_BLOCKS, 256, 0, stream>>>(p, loc_t, conf_t, ws);
    ssd_finish<<<NB, 256, 0, stream>>>(p, conf_t, ws, out);
}